// Round 1
// baseline (2638.887 us; speedup 1.0000x reference)
//
#include <hip/hip_runtime.h>
#include <cstdint>
#include <cstddef>

#define N_ROWS 16384
#define CDIM_C 512
#define HDIM_C 1024
#define FDIM_C 512
#define KMIX 5

typedef unsigned short u16;
typedef __attribute__((ext_vector_type(8))) short bf16x8;
typedef __attribute__((ext_vector_type(4))) float f32x4;

__device__ __forceinline__ u16 f2bf(float x) {
  unsigned u = __float_as_uint(x);
  unsigned r = (u + 0x7fffu + ((u >> 16) & 1u)) >> 16;
  return (u16)r;
}
__device__ __forceinline__ float bf2f(u16 h) {
  return __uint_as_float(((unsigned)h) << 16);
}

__device__ __forceinline__ void gload_lds16(const void* g, void* l) {
  __builtin_amdgcn_global_load_lds((const __attribute__((address_space(1))) void*)g,
                                   (__attribute__((address_space(3))) void*)l,
                                   16, 0, 0);
}

// ---------------------------------------------------------------------------
// split c (3-way bf16 Dekker split, exact 24-bit capture)
// ---------------------------------------------------------------------------
__global__ void split3_kernel(const float* __restrict__ x, u16* __restrict__ P0,
                              u16* __restrict__ P1, u16* __restrict__ P2, size_t n) {
  for (size_t i = (size_t)blockIdx.x * 256 + threadIdx.x; i < n; i += (size_t)gridDim.x * 256) {
    const float v = x[i];
    const u16 h = f2bf(v); const float hf = bf2f(h);
    const u16 m = f2bf(v - hf); const float mf = bf2f(m);
    P0[i] = h; P1[i] = m; P2[i] = f2bf(v - hf - mf);
  }
}

// ---------------------------------------------------------------------------
// transpose W[R][C] -> planes [C][R] with 2- or 3-way split
// ---------------------------------------------------------------------------
template <int NP>
__global__ void transp_split_kernel(const float* __restrict__ W, u16* __restrict__ P0,
                                    u16* __restrict__ P1, u16* __restrict__ P2,
                                    int R, int C) {
  __shared__ float t[32][33];
  const int bz = blockIdx.z;
  const float* Wz = W + (size_t)bz * R * C;
  const size_t oofs = (size_t)bz * R * C;
  const int r0 = blockIdx.x * 32, c0 = blockIdx.y * 32;
  const int tx = threadIdx.x, ty = threadIdx.y;  // (32,8)
#pragma unroll
  for (int i = 0; i < 4; ++i)
    t[ty + i * 8][tx] = Wz[(size_t)(r0 + ty + i * 8) * C + c0 + tx];
  __syncthreads();
#pragma unroll
  for (int i = 0; i < 4; ++i) {
    const int c = c0 + ty + i * 8, r = r0 + tx;
    const float x = t[tx][ty + i * 8];
    const size_t idx = oofs + (size_t)c * R + r;
    const u16 h = f2bf(x);
    P0[idx] = h;
    const float hf = bf2f(h);
    const u16 m = f2bf(x - hf);
    P1[idx] = m;
    if (NP >= 3) {
      const float mf = bf2f(m);
      P2[idx] = f2bf(x - hf - mf);
    }
  }
}

// ---------------------------------------------------------------------------
// split-precision MFMA GEMM: C[M][Nc] = sum_terms A_p[M][Kd] @ B_q[Nc][Kd]^T
// A planes row-major [M][Kd]; B planes pre-transposed [Nc][Kd].
// 128x128 tile, BK=32, 4 waves (2x2), 4x4 16x16x32 fragments per wave.
// Epilogue: +bias[col], optional relu, output fp32 or re-split bf16 planes.
// ---------------------------------------------------------------------------
template <int NA, int NB, int NT, bool RELU, int OSPL>
__global__ __launch_bounds__(256, 2) void gemm_split(
    const u16* __restrict__ A0, const u16* __restrict__ A1, const u16* __restrict__ A2,
    const u16* __restrict__ B0, const u16* __restrict__ B1, const u16* __restrict__ B2,
    const float* __restrict__ bias, float* __restrict__ outF,
    u16* __restrict__ O0, u16* __restrict__ O1, u16* __restrict__ O2,
    int M, int Nc, int Kd) {
  __shared__ u16 lds[(NA + NB) * 4096];  // per plane: [4 kb][128 rows][8 bf16] = 8 KB
  const int tid = threadIdx.x;
  const int lane = tid & 63;
  const int wave = tid >> 6;
  const int wm = wave >> 1, wn = wave & 1;
  const int col0 = blockIdx.x * 128;
  const int row0 = blockIdx.y * 128;
  const u16* Ap[3] = {A0, A1, A2};
  const u16* Bp[3] = {B0, B1, B2};
  constexpr int TA[6] = {0, 0, 1, 1, 0, 2};
  constexpr int TB[6] = {0, 1, 0, 1, 2, 0};

  f32x4 acc[4][4] = {};
  const int kb = lane >> 4;
  const int rl = lane & 15;
  const int nSteps = Kd >> 5;

  for (int kt = 0; kt < nSteps; ++kt) {
    const int k0 = kt << 5;
    __syncthreads();  // previous compute done before overwrite
#pragma unroll
    for (int p = 0; p < NA + NB; ++p) {
      const u16* gp = (p < NA) ? Ap[p] : Bp[p - NA];
      const int rb = (p < NA) ? row0 : col0;
      u16* lbase = &lds[p * 4096];
#pragma unroll
      for (int it = 0; it < 2; ++it) {
        const int sbase = it * 256 + wave * 64;  // wave-uniform slot base
        const int slot = sbase + lane;
        const int skb = slot >> 7;
        const int sr = slot & 127;
        const u16* src = gp + (size_t)(rb + sr) * Kd + (k0 + skb * 8);
        gload_lds16(src, lbase + sbase * 8);
      }
    }
    __syncthreads();  // drains vmcnt: staged tiles visible

    bf16x8 aF[NA][4];
    bf16x8 bF[NB][4];
#pragma unroll
    for (int p = 0; p < NA; ++p)
#pragma unroll
      for (int i = 0; i < 4; ++i) {
        const int r = wm * 64 + i * 16 + rl;
        aF[p][i] = *(const bf16x8*)&lds[p * 4096 + (kb * 128 + r) * 8];
      }
#pragma unroll
    for (int p = 0; p < NB; ++p)
#pragma unroll
      for (int j = 0; j < 4; ++j) {
        const int r = wn * 64 + j * 16 + rl;
        bF[p][j] = *(const bf16x8*)&lds[(NA + p) * 4096 + (kb * 128 + r) * 8];
      }
#pragma unroll
    for (int t = 0; t < NT; ++t)
#pragma unroll
      for (int i = 0; i < 4; ++i)
#pragma unroll
        for (int j = 0; j < 4; ++j)
          acc[i][j] = __builtin_amdgcn_mfma_f32_16x16x32_bf16(
              aF[TA[t]][i], bF[TB[t]][j], acc[i][j], 0, 0, 0);
  }

  // epilogue: D layout col = lane&15, row = (lane>>4)*4 + r  [m89/m91 verified]
#pragma unroll
  for (int i = 0; i < 4; ++i)
#pragma unroll
    for (int j = 0; j < 4; ++j)
#pragma unroll
      for (int r = 0; r < 4; ++r) {
        const int row = row0 + wm * 64 + i * 16 + (lane >> 4) * 4 + r;
        const int col = col0 + wn * 64 + j * 16 + (lane & 15);
        float y = acc[i][j][r] + bias[col];
        if (RELU) y = fmaxf(y, 0.0f);
        const size_t idx = (size_t)row * Nc + col;
        if constexpr (OSPL == 0) {
          outF[idx] = y;
        } else {
          const u16 h = f2bf(y);
          const float hf = bf2f(h);
          const u16 m = f2bf(y - hf);
          O0[idx] = h;
          O1[idx] = m;
          if constexpr (OSPL == 3) {
            const float mf = bf2f(m);
            O2[idx] = f2bf(y - hf - mf);
          }
        }
      }
  (void)M;
}

// ---------------------------------------------------------------------------
// logits = h2 @ pw2 + pb2 ; softmax ; gumbel ; argmax ; mixture weights
// one wave per row, fp64 accumulation (argmax flip protection)
// ---------------------------------------------------------------------------
__global__ void p2_weights_kernel(const float* __restrict__ h2, const float* __restrict__ pw2,
                                  const float* __restrict__ pb2, const float* __restrict__ gu,
                                  float* __restrict__ w) {
  const int n = blockIdx.x * 4 + (threadIdx.x >> 6);
  const int lane = threadIdx.x & 63;
  const float* hrow = h2 + (size_t)n * HDIM_C;
  double acc[KMIX] = {0, 0, 0, 0, 0};
  const int c0 = lane * 16;
#pragma unroll
  for (int jj = 0; jj < 16; ++jj) {
    const int cc = c0 + jj;
    const double hv = (double)hrow[cc];
#pragma unroll
    for (int kk = 0; kk < KMIX; ++kk)
      acc[kk] += hv * (double)pw2[cc * KMIX + kk];
  }
#pragma unroll
  for (int offs = 32; offs >= 1; offs >>= 1)
#pragma unroll
    for (int kk = 0; kk < KMIX; ++kk)
      acc[kk] += __shfl_down(acc[kk], offs);
  if (lane == 0) {
    double lg[KMIX], mx = -1e300;
#pragma unroll
    for (int kk = 0; kk < KMIX; ++kk) {
      lg[kk] = acc[kk] + (double)pb2[kk];
      if (lg[kk] > mx) mx = lg[kk];
    }
    double e[KMIX], s = 0.0;
#pragma unroll
    for (int kk = 0; kk < KMIX; ++kk) { e[kk] = exp(lg[kk] - mx); s += e[kk]; }
    int idx = 0; double zb = -1e300;
#pragma unroll
    for (int kk = 0; kk < KMIX; ++kk) {
      const double ps = e[kk] / s;
      const double u = (double)gu[n * KMIX + kk];
      const double g = -log(-log(u + 1e-20) + 1e-20);
      const double zz = log(ps + 1e-20) + g;
      if (zz > zb) { zb = zz; idx = kk; }  // strict > keeps first index (jnp.argmax)
    }
#pragma unroll
    for (int kk = 0; kk < KMIX; ++kk)
      w[n * KMIX + kk] = (float)((e[kk] / s + (kk == idx ? 5.0 : 0.0)) / 6.0);
  }
}

// ---------------------------------------------------------------------------
// mix: out[n][f] (+)= w[n][k] * (mean + noise * exp(0.5*logvar))
// o = [N][1024] with mean cols 0..511, logvar cols 512..1023
// ---------------------------------------------------------------------------
template <bool FIRST>
__global__ void mix_kernel(const float* __restrict__ o, const float* __restrict__ nz,
                           const float* __restrict__ w, float* __restrict__ out, int k) {
  const int i = blockIdx.x * 256 + threadIdx.x;  // vec4 index, total N*128
  const int n = i >> 7;
  const int fv = i & 127;
  const float wk = w[n * KMIX + k];
  const float4 me = *(const float4*)(o + (size_t)n * HDIM_C + fv * 4);
  const float4 lv = *(const float4*)(o + (size_t)n * HDIM_C + FDIM_C + fv * 4);
  const float4 nv = *(const float4*)(nz + (size_t)n * FDIM_C + fv * 4);
  float4 r;
  r.x = wk * (me.x + nv.x * expf(0.5f * lv.x));
  r.y = wk * (me.y + nv.y * expf(0.5f * lv.y));
  r.z = wk * (me.z + nv.z * expf(0.5f * lv.z));
  r.w = wk * (me.w + nv.w * expf(0.5f * lv.w));
  float4* op = (float4*)out + i;
  if (FIRST) {
    *op = r;
  } else {
    float4 p = *op;
    p.x += r.x; p.y += r.y; p.z += r.z; p.w += r.w;
    *op = p;
  }
}

// ---------------------------------------------------------------------------
extern "C" void kernel_launch(void* const* d_in, const int* in_sizes, int n_in,
                              void* d_out, int out_size, void* d_ws, size_t ws_size,
                              hipStream_t stream) {
  const float* c   = (const float*)d_in[0];
  // d_in[1] = x, unused by the reference
  const float* noise = (const float*)d_in[2];
  const float* gu  = (const float*)d_in[3];
  const float* pw0 = (const float*)d_in[4];
  const float* pb0 = (const float*)d_in[5];
  const float* pw1 = (const float*)d_in[6];
  const float* pb1 = (const float*)d_in[7];
  const float* pw2 = (const float*)d_in[8];
  const float* pb2 = (const float*)d_in[9];
  const float* gw0 = (const float*)d_in[10];
  const float* gb0 = (const float*)d_in[11];
  const float* gw1 = (const float*)d_in[12];
  const float* gb1 = (const float*)d_in[13];
  const float* gw2 = (const float*)d_in[14];
  const float* gb2 = (const float*)d_in[15];
  float* out = (float*)d_out;

  char* ws = (char*)d_ws;
  size_t off = 0;
  auto alloc = [&](size_t bytes) -> char* {
    off = (off + 255) & ~(size_t)255;
    char* p = ws + off;
    off += bytes;
    return p;
  };

  const size_t NCp = (size_t)N_ROWS * CDIM_C * 2;  // bf16 plane of c
  const size_t NHp = (size_t)N_ROWS * HDIM_C * 2;  // bf16 plane [N][1024]
  u16* cH = (u16*)alloc(NCp);
  u16* cM = (u16*)alloc(NCp);
  u16* cL = (u16*)alloc(NCp);
  u16* pw0T0 = (u16*)alloc((size_t)CDIM_C * HDIM_C * 2);
  u16* pw0T1 = (u16*)alloc((size_t)CDIM_C * HDIM_C * 2);
  u16* pw0T2 = (u16*)alloc((size_t)CDIM_C * HDIM_C * 2);
  u16* pw1T0 = (u16*)alloc((size_t)HDIM_C * HDIM_C * 2);
  u16* pw1T1 = (u16*)alloc((size_t)HDIM_C * HDIM_C * 2);
  u16* pw1T2 = (u16*)alloc((size_t)HDIM_C * HDIM_C * 2);
  u16* hH = (u16*)alloc(NHp);
  u16* hM = (u16*)alloc(NHp);
  u16* hL = (u16*)alloc(NHp);
  float* h2 = (float*)alloc((size_t)N_ROWS * HDIM_C * 4);
  float* wbuf = (float*)alloc((size_t)N_ROWS * KMIX * 4);
  u16* gw0T0 = (u16*)alloc((size_t)KMIX * CDIM_C * HDIM_C * 2);
  u16* gw0T1 = (u16*)alloc((size_t)KMIX * CDIM_C * HDIM_C * 2);
  u16* gw1T0 = (u16*)alloc((size_t)KMIX * HDIM_C * HDIM_C * 2);
  u16* gw1T1 = (u16*)alloc((size_t)KMIX * HDIM_C * HDIM_C * 2);
  u16* gw2T0 = (u16*)alloc((size_t)KMIX * HDIM_C * HDIM_C * 2);
  u16* gw2T1 = (u16*)alloc((size_t)KMIX * HDIM_C * HDIM_C * 2);
  u16* g2b = (u16*)alloc(NHp);
  // buffer reuse (all stream-serialized, producers dead before overwrite):
  u16* g1a = hH;   // h planes dead after P1
  u16* g1b = hM;
  u16* g2a = hL;
  float* obuf = h2;  // h2 dead after p2_weights
  (void)ws_size; (void)in_sizes; (void)n_in; (void)out_size;

  // ---- prep ----
  split3_kernel<<<2048, 256, 0, stream>>>(c, cH, cM, cL, (size_t)N_ROWS * CDIM_C);
  transp_split_kernel<3><<<dim3(CDIM_C / 32, HDIM_C / 32, 1), dim3(32, 8), 0, stream>>>(
      pw0, pw0T0, pw0T1, pw0T2, CDIM_C, HDIM_C);
  transp_split_kernel<3><<<dim3(HDIM_C / 32, HDIM_C / 32, 1), dim3(32, 8), 0, stream>>>(
      pw1, pw1T0, pw1T1, pw1T2, HDIM_C, HDIM_C);
  transp_split_kernel<2><<<dim3(CDIM_C / 32, HDIM_C / 32, KMIX), dim3(32, 8), 0, stream>>>(
      gw0, gw0T0, gw0T1, nullptr, CDIM_C, HDIM_C);
  transp_split_kernel<2><<<dim3(HDIM_C / 32, HDIM_C / 32, KMIX), dim3(32, 8), 0, stream>>>(
      gw1, gw1T0, gw1T1, nullptr, HDIM_C, HDIM_C);
  transp_split_kernel<2><<<dim3(HDIM_C / 32, HDIM_C / 32, KMIX), dim3(32, 8), 0, stream>>>(
      gw2, gw2T0, gw2T1, nullptr, HDIM_C, HDIM_C);

  const dim3 gg(HDIM_C / 128, N_ROWS / 128);

  // ---- P network (6-pass, ~fp32-exact for argmax safety) ----
  gemm_split<3, 3, 6, true, 3><<<gg, 256, 0, stream>>>(
      cH, cM, cL, pw0T0, pw0T1, pw0T2, pb0, nullptr, hH, hM, hL,
      N_ROWS, HDIM_C, CDIM_C);
  gemm_split<3, 3, 6, true, 0><<<gg, 256, 0, stream>>>(
      hH, hM, hL, pw1T0, pw1T1, pw1T2, pb1, h2, nullptr, nullptr, nullptr,
      N_ROWS, HDIM_C, HDIM_C);
  p2_weights_kernel<<<N_ROWS / 4, 256, 0, stream>>>(h2, pw2, pb2, gu, wbuf);

  // ---- G network (3-pass per expert) + mix ----
  for (int k = 0; k < KMIX; ++k) {
    gemm_split<2, 2, 3, true, 2><<<gg, 256, 0, stream>>>(
        cH, cM, nullptr,
        gw0T0 + (size_t)k * CDIM_C * HDIM_C, gw0T1 + (size_t)k * CDIM_C * HDIM_C, nullptr,
        gb0 + k * HDIM_C, nullptr, g1a, g1b, nullptr,
        N_ROWS, HDIM_C, CDIM_C);
    gemm_split<2, 2, 3, true, 2><<<gg, 256, 0, stream>>>(
        g1a, g1b, nullptr,
        gw1T0 + (size_t)k * HDIM_C * HDIM_C, gw1T1 + (size_t)k * HDIM_C * HDIM_C, nullptr,
        gb1 + k * HDIM_C, nullptr, g2a, g2b, nullptr,
        N_ROWS, HDIM_C, HDIM_C);
    gemm_split<2, 2, 3, false, 0><<<gg, 256, 0, stream>>>(
        g2a, g2b, nullptr,
        gw2T0 + (size_t)k * HDIM_C * HDIM_C, gw2T1 + (size_t)k * HDIM_C * HDIM_C, nullptr,
        gb2 + k * HDIM_C, obuf, nullptr, nullptr, nullptr,
        N_ROWS, HDIM_C, HDIM_C);
    if (k == 0)
      mix_kernel<true><<<N_ROWS * 128 / 256, 256, 0, stream>>>(
          obuf, noise + (size_t)k * N_ROWS * FDIM_C, wbuf, out, k);
    else
      mix_kernel<false><<<N_ROWS * 128 / 256, 256, 0, stream>>>(
          obuf, noise + (size_t)k * N_ROWS * FDIM_C, wbuf, out, k);
  }
}

// Round 2
// 2470.078 us; speedup vs baseline: 1.0683x; 1.0683x over previous
//
#include <hip/hip_runtime.h>
#include <cstdint>
#include <cstddef>

#define N_ROWS 16384
#define CDIM_C 512
#define HDIM_C 1024
#define FDIM_C 512
#define KMIX 5

typedef unsigned short u16;
typedef __attribute__((ext_vector_type(8))) short bf16x8;
typedef __attribute__((ext_vector_type(4))) float f32x4;

__device__ __forceinline__ u16 f2bf(float x) {
  unsigned u = __float_as_uint(x);
  unsigned r = (u + 0x7fffu + ((u >> 16) & 1u)) >> 16;
  return (u16)r;
}
__device__ __forceinline__ float bf2f(u16 h) {
  return __uint_as_float(((unsigned)h) << 16);
}

__device__ __forceinline__ void gload_lds16(const void* g, void* l) {
  __builtin_amdgcn_global_load_lds((const __attribute__((address_space(1))) void*)g,
                                   (__attribute__((address_space(3))) void*)l,
                                   16, 0, 0);
}

// ---------------------------------------------------------------------------
// split c (3-way bf16 Dekker split, exact 24-bit capture)
// ---------------------------------------------------------------------------
__global__ void split3_kernel(const float* __restrict__ x, u16* __restrict__ P0,
                              u16* __restrict__ P1, u16* __restrict__ P2, size_t n) {
  for (size_t i = (size_t)blockIdx.x * 256 + threadIdx.x; i < n; i += (size_t)gridDim.x * 256) {
    const float v = x[i];
    const u16 h = f2bf(v); const float hf = bf2f(h);
    const u16 m = f2bf(v - hf); const float mf = bf2f(m);
    P0[i] = h; P1[i] = m; P2[i] = f2bf(v - hf - mf);
  }
}

// ---------------------------------------------------------------------------
// transpose W[R][C] -> planes [C][R] with 2- or 3-way split.
// PERM: interleave mean/logvar columns (c<512 -> 2c, c>=512 -> 2(c-512)+1)
// so the G2 output tile holds (mean_f, logvar_f) in adjacent columns.
// ---------------------------------------------------------------------------
template <int NP, bool PERM>
__global__ void transp_split_kernel(const float* __restrict__ W, u16* __restrict__ P0,
                                    u16* __restrict__ P1, u16* __restrict__ P2,
                                    int R, int C) {
  __shared__ float t[32][33];
  const int bz = blockIdx.z;
  const float* Wz = W + (size_t)bz * R * C;
  const size_t oofs = (size_t)bz * R * C;
  const int r0 = blockIdx.x * 32, c0 = blockIdx.y * 32;
  const int tx = threadIdx.x, ty = threadIdx.y;  // (32,8)
#pragma unroll
  for (int i = 0; i < 4; ++i)
    t[ty + i * 8][tx] = Wz[(size_t)(r0 + ty + i * 8) * C + c0 + tx];
  __syncthreads();
#pragma unroll
  for (int i = 0; i < 4; ++i) {
    const int c_raw = c0 + ty + i * 8, r = r0 + tx;
    const int c = PERM ? ((c_raw < FDIM_C) ? (c_raw * 2) : ((c_raw - FDIM_C) * 2 + 1)) : c_raw;
    const float x = t[tx][ty + i * 8];
    const size_t idx = oofs + (size_t)c * R + r;
    const u16 h = f2bf(x);
    P0[idx] = h;
    const float hf = bf2f(h);
    const u16 m = f2bf(x - hf);
    P1[idx] = m;
    if (NP >= 3) {
      const float mf = bf2f(m);
      P2[idx] = f2bf(x - hf - mf);
    }
  }
}

// ---------------------------------------------------------------------------
// split-precision MFMA GEMM: C[M][Nc] = sum_terms A_p[M][Kd] @ B_q[Nc][Kd]^T
// 128x128 tile, BK=32, 4 waves, 4x4 16x16x32 fragments per wave.
// Grid is ALWAYS (8, M/128): XCD-bijective swizzle assumes gx==8, nwg%8==0.
// MIX: fused sample+mixture epilogue (gw2 columns pre-permuted; pairs via shfl).
// ---------------------------------------------------------------------------
template <int NA, int NB, int NT, bool RELU, int OSPL, int MIX, int BPC>
__global__ __launch_bounds__(256, BPC) void gemm_split(
    const u16* __restrict__ A0, const u16* __restrict__ A1, const u16* __restrict__ A2,
    const u16* __restrict__ B0, const u16* __restrict__ B1, const u16* __restrict__ B2,
    const float* __restrict__ bias, float* __restrict__ outF,
    u16* __restrict__ O0, u16* __restrict__ O1, u16* __restrict__ O2,
    const float* __restrict__ noise_k, const float* __restrict__ wvec,
    float* __restrict__ mixout, int kidx,
    int M, int Nc, int Kd) {
  __shared__ u16 lds[(NA + NB) * 4096];  // per plane: [4 kb][128 rows][8 bf16] = 8 KB
  const int tid = threadIdx.x;
  const int lane = tid & 63;
  const int wave = tid >> 6;
  const int wm = wave >> 1, wn = wave & 1;

  // T1: bijective XCD swizzle (gx==8, gy==M/128, nwg divisible by 8)
  const int nwg = (int)(gridDim.x * gridDim.y);
  const int orig = (int)(blockIdx.y * gridDim.x + blockIdx.x);
  const int cpx = nwg >> 3;
  const int wg = (orig & 7) * cpx + (orig >> 3);
  const int col0 = (wg & 7) * 128;
  const int row0 = (wg >> 3) * 128;

  const u16* Ap[3] = {A0, A1, A2};
  const u16* Bp[3] = {B0, B1, B2};
  constexpr int TA[6] = {0, 0, 1, 1, 0, 2};
  constexpr int TB[6] = {0, 1, 0, 1, 2, 0};

  f32x4 acc[4][4] = {};
  const int kb = lane >> 4;
  const int rl = lane & 15;
  const int nSteps = Kd >> 5;

  for (int kt = 0; kt < nSteps; ++kt) {
    const int k0 = kt << 5;
    __syncthreads();  // previous compute done before overwrite
#pragma unroll
    for (int p = 0; p < NA + NB; ++p) {
      const u16* gp = (p < NA) ? Ap[p] : Bp[p - NA];
      const int rb = (p < NA) ? row0 : col0;
      u16* lbase = &lds[p * 4096];
#pragma unroll
      for (int it = 0; it < 2; ++it) {
        const int sbase = it * 256 + wave * 64;  // wave-uniform slot base
        const int slot = sbase + lane;
        const int skb = slot >> 7;
        const int sr = slot & 127;
        const u16* src = gp + (size_t)(rb + sr) * Kd + (k0 + skb * 8);
        gload_lds16(src, lbase + sbase * 8);
      }
    }
    __syncthreads();  // drains vmcnt: staged tiles visible

    bf16x8 aF[NA][4];
    bf16x8 bF[NB][4];
#pragma unroll
    for (int p = 0; p < NA; ++p)
#pragma unroll
      for (int i = 0; i < 4; ++i) {
        const int r = wm * 64 + i * 16 + rl;
        aF[p][i] = *(const bf16x8*)&lds[p * 4096 + (kb * 128 + r) * 8];
      }
#pragma unroll
    for (int p = 0; p < NB; ++p)
#pragma unroll
      for (int j = 0; j < 4; ++j) {
        const int r = wn * 64 + j * 16 + rl;
        bF[p][j] = *(const bf16x8*)&lds[(NA + p) * 4096 + (kb * 128 + r) * 8];
      }
#pragma unroll
    for (int t = 0; t < NT; ++t)
#pragma unroll
      for (int i = 0; i < 4; ++i)
#pragma unroll
        for (int j = 0; j < 4; ++j)
          acc[i][j] = __builtin_amdgcn_mfma_f32_16x16x32_bf16(
              aF[TA[t]][i], bF[TB[t]][j], acc[i][j], 0, 0, 0);
  }

  // epilogue: D layout col = lane&15, row = (lane>>4)*4 + r  [m89/m91 verified]
#pragma unroll
  for (int i = 0; i < 4; ++i)
#pragma unroll
    for (int j = 0; j < 4; ++j)
#pragma unroll
      for (int r = 0; r < 4; ++r) {
        const int row = row0 + wm * 64 + i * 16 + (lane >> 4) * 4 + r;
        const int col = col0 + wn * 64 + j * 16 + (lane & 15);
        if constexpr (MIX > 0) {
          // col is in permuted space: even = mean_f, odd = logvar_f, f = col>>1
          const int f = col >> 1;
          const int ocol = (col & 1) ? (f + FDIM_C) : f;
          const float y = acc[i][j][r] + bias[ocol];
          const float other = __shfl_xor(y, 1);
          if (!(lane & 1)) {
            const float sample = y + noise_k[(size_t)row * FDIM_C + f] * expf(0.5f * other);
            const float v = wvec[row * KMIX + kidx] * sample;
            float* op = &mixout[(size_t)row * FDIM_C + f];
            if constexpr (MIX == 1) *op = v; else *op += v;
          }
        } else {
          float y = acc[i][j][r] + bias[col];
          if (RELU) y = fmaxf(y, 0.0f);
          const size_t idx = (size_t)row * Nc + col;
          if constexpr (OSPL == 0) {
            outF[idx] = y;
          } else {
            const u16 h = f2bf(y);
            const float hf = bf2f(h);
            const u16 m = f2bf(y - hf);
            O0[idx] = h;
            O1[idx] = m;
            if constexpr (OSPL == 3) {
              const float mf = bf2f(m);
              O2[idx] = f2bf(y - hf - mf);
            }
          }
        }
      }
  (void)M;
}

// ---------------------------------------------------------------------------
// logits = h2 @ pw2 + pb2 ; softmax ; gumbel ; argmax ; mixture weights
// one wave per row, fp64 accumulation (argmax flip protection)
// ---------------------------------------------------------------------------
__global__ void p2_weights_kernel(const float* __restrict__ h2, const float* __restrict__ pw2,
                                  const float* __restrict__ pb2, const float* __restrict__ gu,
                                  float* __restrict__ w) {
  const int n = blockIdx.x * 4 + (threadIdx.x >> 6);
  const int lane = threadIdx.x & 63;
  const float* hrow = h2 + (size_t)n * HDIM_C;
  double acc[KMIX] = {0, 0, 0, 0, 0};
  const int c0 = lane * 16;
#pragma unroll
  for (int jj = 0; jj < 16; ++jj) {
    const int cc = c0 + jj;
    const double hv = (double)hrow[cc];
#pragma unroll
    for (int kk = 0; kk < KMIX; ++kk)
      acc[kk] += hv * (double)pw2[cc * KMIX + kk];
  }
#pragma unroll
  for (int offs = 32; offs >= 1; offs >>= 1)
#pragma unroll
    for (int kk = 0; kk < KMIX; ++kk)
      acc[kk] += __shfl_down(acc[kk], offs);
  if (lane == 0) {
    double lg[KMIX], mx = -1e300;
#pragma unroll
    for (int kk = 0; kk < KMIX; ++kk) {
      lg[kk] = acc[kk] + (double)pb2[kk];
      if (lg[kk] > mx) mx = lg[kk];
    }
    double e[KMIX], s = 0.0;
#pragma unroll
    for (int kk = 0; kk < KMIX; ++kk) { e[kk] = exp(lg[kk] - mx); s += e[kk]; }
    int idx = 0; double zb = -1e300;
#pragma unroll
    for (int kk = 0; kk < KMIX; ++kk) {
      const double ps = e[kk] / s;
      const double u = (double)gu[n * KMIX + kk];
      const double g = -log(-log(u + 1e-20) + 1e-20);
      const double zz = log(ps + 1e-20) + g;
      if (zz > zb) { zb = zz; idx = kk; }  // strict > keeps first index (jnp.argmax)
    }
#pragma unroll
    for (int kk = 0; kk < KMIX; ++kk)
      w[n * KMIX + kk] = (float)((e[kk] / s + (kk == idx ? 5.0 : 0.0)) / 6.0);
  }
}

// ---------------------------------------------------------------------------
extern "C" void kernel_launch(void* const* d_in, const int* in_sizes, int n_in,
                              void* d_out, int out_size, void* d_ws, size_t ws_size,
                              hipStream_t stream) {
  const float* c   = (const float*)d_in[0];
  // d_in[1] = x, unused by the reference
  const float* noise = (const float*)d_in[2];
  const float* gu  = (const float*)d_in[3];
  const float* pw0 = (const float*)d_in[4];
  const float* pb0 = (const float*)d_in[5];
  const float* pw1 = (const float*)d_in[6];
  const float* pb1 = (const float*)d_in[7];
  const float* pw2 = (const float*)d_in[8];
  const float* pb2 = (const float*)d_in[9];
  const float* gw0 = (const float*)d_in[10];
  const float* gb0 = (const float*)d_in[11];
  const float* gw1 = (const float*)d_in[12];
  const float* gb1 = (const float*)d_in[13];
  const float* gw2 = (const float*)d_in[14];
  const float* gb2 = (const float*)d_in[15];
  float* out = (float*)d_out;

  char* ws = (char*)d_ws;
  size_t off = 0;
  auto alloc = [&](size_t bytes) -> char* {
    off = (off + 255) & ~(size_t)255;
    char* p = ws + off;
    off += bytes;
    return p;
  };

  const size_t NCp = (size_t)N_ROWS * CDIM_C * 2;  // bf16 plane of c
  const size_t NHp = (size_t)N_ROWS * HDIM_C * 2;  // bf16 plane [N][1024]
  u16* cH = (u16*)alloc(NCp);
  u16* cM = (u16*)alloc(NCp);
  u16* cL = (u16*)alloc(NCp);
  u16* pw0T0 = (u16*)alloc((size_t)CDIM_C * HDIM_C * 2);
  u16* pw0T1 = (u16*)alloc((size_t)CDIM_C * HDIM_C * 2);
  u16* pw0T2 = (u16*)alloc((size_t)CDIM_C * HDIM_C * 2);
  u16* pw1T0 = (u16*)alloc((size_t)HDIM_C * HDIM_C * 2);
  u16* pw1T1 = (u16*)alloc((size_t)HDIM_C * HDIM_C * 2);
  u16* pw1T2 = (u16*)alloc((size_t)HDIM_C * HDIM_C * 2);
  u16* hH = (u16*)alloc(NHp);
  u16* hM = (u16*)alloc(NHp);
  u16* hL = (u16*)alloc(NHp);
  float* h2 = (float*)alloc((size_t)N_ROWS * HDIM_C * 4);
  float* wbuf = (float*)alloc((size_t)N_ROWS * KMIX * 4);
  u16* gw0T0 = (u16*)alloc((size_t)KMIX * CDIM_C * HDIM_C * 2);
  u16* gw0T1 = (u16*)alloc((size_t)KMIX * CDIM_C * HDIM_C * 2);
  u16* gw1T0 = (u16*)alloc((size_t)KMIX * HDIM_C * HDIM_C * 2);
  u16* gw1T1 = (u16*)alloc((size_t)KMIX * HDIM_C * HDIM_C * 2);
  u16* gw2T0 = (u16*)alloc((size_t)KMIX * HDIM_C * HDIM_C * 2);
  u16* gw2T1 = (u16*)alloc((size_t)KMIX * HDIM_C * HDIM_C * 2);
  u16* g2b = (u16*)alloc(NHp);
  // buffer reuse (all stream-serialized, producers dead before overwrite):
  u16* g1a = hH;   // h planes dead after P1
  u16* g1b = hM;
  u16* g2a = hL;
  (void)ws_size; (void)in_sizes; (void)n_in; (void)out_size;

  // ---- prep ----
  split3_kernel<<<2048, 256, 0, stream>>>(c, cH, cM, cL, (size_t)N_ROWS * CDIM_C);
  transp_split_kernel<3, false><<<dim3(CDIM_C / 32, HDIM_C / 32, 1), dim3(32, 8), 0, stream>>>(
      pw0, pw0T0, pw0T1, pw0T2, CDIM_C, HDIM_C);
  transp_split_kernel<3, false><<<dim3(HDIM_C / 32, HDIM_C / 32, 1), dim3(32, 8), 0, stream>>>(
      pw1, pw1T0, pw1T1, pw1T2, HDIM_C, HDIM_C);
  transp_split_kernel<2, false><<<dim3(CDIM_C / 32, HDIM_C / 32, KMIX), dim3(32, 8), 0, stream>>>(
      gw0, gw0T0, gw0T1, nullptr, CDIM_C, HDIM_C);
  transp_split_kernel<2, false><<<dim3(HDIM_C / 32, HDIM_C / 32, KMIX), dim3(32, 8), 0, stream>>>(
      gw1, gw1T0, gw1T1, nullptr, HDIM_C, HDIM_C);
  transp_split_kernel<2, true><<<dim3(HDIM_C / 32, HDIM_C / 32, KMIX), dim3(32, 8), 0, stream>>>(
      gw2, gw2T0, gw2T1, nullptr, HDIM_C, HDIM_C);

  const dim3 gg(HDIM_C / 128, N_ROWS / 128);

  // ---- P network (6-pass, ~fp32-exact for argmax safety) ----
  gemm_split<3, 3, 6, true, 3, 0, 3><<<gg, 256, 0, stream>>>(
      cH, cM, cL, pw0T0, pw0T1, pw0T2, pb0, nullptr, hH, hM, hL,
      nullptr, nullptr, nullptr, 0, N_ROWS, HDIM_C, CDIM_C);
  gemm_split<3, 3, 6, true, 0, 0, 3><<<gg, 256, 0, stream>>>(
      hH, hM, hL, pw1T0, pw1T1, pw1T2, pb1, h2, nullptr, nullptr, nullptr,
      nullptr, nullptr, nullptr, 0, N_ROWS, HDIM_C, HDIM_C);
  p2_weights_kernel<<<N_ROWS / 4, 256, 0, stream>>>(h2, pw2, pb2, gu, wbuf);

  // ---- G network (3-pass per expert), mix fused into G2 epilogue ----
  for (int k = 0; k < KMIX; ++k) {
    gemm_split<2, 2, 3, true, 2, 0, 4><<<gg, 256, 0, stream>>>(
        cH, cM, nullptr,
        gw0T0 + (size_t)k * CDIM_C * HDIM_C, gw0T1 + (size_t)k * CDIM_C * HDIM_C, nullptr,
        gb0 + k * HDIM_C, nullptr, g1a, g1b, nullptr,
        nullptr, nullptr, nullptr, 0, N_ROWS, HDIM_C, CDIM_C);
    gemm_split<2, 2, 3, true, 2, 0, 4><<<gg, 256, 0, stream>>>(
        g1a, g1b, nullptr,
        gw1T0 + (size_t)k * HDIM_C * HDIM_C, gw1T1 + (size_t)k * HDIM_C * HDIM_C, nullptr,
        gb1 + k * HDIM_C, nullptr, g2a, g2b, nullptr,
        nullptr, nullptr, nullptr, 0, N_ROWS, HDIM_C, HDIM_C);
    if (k == 0)
      gemm_split<2, 2, 3, false, 0, 1, 4><<<gg, 256, 0, stream>>>(
          g2a, g2b, nullptr,
          gw2T0 + (size_t)k * HDIM_C * HDIM_C, gw2T1 + (size_t)k * HDIM_C * HDIM_C, nullptr,
          gb2 + k * HDIM_C, nullptr, nullptr, nullptr, nullptr,
          noise + (size_t)k * N_ROWS * FDIM_C, wbuf, out, k, N_ROWS, HDIM_C, HDIM_C);
    else
      gemm_split<2, 2, 3, false, 0, 2, 4><<<gg, 256, 0, stream>>>(
          g2a, g2b, nullptr,
          gw2T0 + (size_t)k * HDIM_C * HDIM_C, gw2T1 + (size_t)k * HDIM_C * HDIM_C, nullptr,
          gb2 + k * HDIM_C, nullptr, nullptr, nullptr, nullptr,
          noise + (size_t)k * N_ROWS * FDIM_C, wbuf, out, k, N_ROWS, HDIM_C, HDIM_C);
  }
}

// Round 4
// 2387.706 us; speedup vs baseline: 1.1052x; 1.0345x over previous
//
#include <hip/hip_runtime.h>
#include <cstdint>
#include <cstddef>

#define N_ROWS 16384
#define CDIM_C 512
#define HDIM_C 1024
#define FDIM_C 512
#define KMIX 5

typedef unsigned short u16;
typedef __attribute__((ext_vector_type(8))) short bf16x8;
typedef __attribute__((ext_vector_type(4))) float f32x4;

__device__ __forceinline__ u16 f2bf(float x) {
  unsigned u = __float_as_uint(x);
  unsigned r = (u + 0x7fffu + ((u >> 16) & 1u)) >> 16;
  return (u16)r;
}
__device__ __forceinline__ float bf2f(u16 h) {
  return __uint_as_float(((unsigned)h) << 16);
}

__device__ __forceinline__ void gload_lds16(const u16* g, u16* l) {
  __builtin_amdgcn_global_load_lds((const __attribute__((address_space(1))) void*)g,
                                   (__attribute__((address_space(3))) void*)l,
                                   16, 0, 0);
}

// ---------------------------------------------------------------------------
// split c (3-way bf16 Dekker split, exact 24-bit capture)
// ---------------------------------------------------------------------------
__global__ void split3_kernel(const float* __restrict__ x, u16* __restrict__ P0,
                              u16* __restrict__ P1, u16* __restrict__ P2, size_t n) {
  for (size_t i = (size_t)blockIdx.x * 256 + threadIdx.x; i < n; i += (size_t)gridDim.x * 256) {
    const float v = x[i];
    const u16 h = f2bf(v); const float hf = bf2f(h);
    const u16 m = f2bf(v - hf); const float mf = bf2f(m);
    P0[i] = h; P1[i] = m; P2[i] = f2bf(v - hf - mf);
  }
}

// ---------------------------------------------------------------------------
// transpose W[R][C] -> planes [C][R] with 2- or 3-way split.
// PERM: interleave mean/logvar columns (c<512 -> 2c, c>=512 -> 2(c-512)+1)
// ---------------------------------------------------------------------------
template <int NP, bool PERM>
__global__ void transp_split_kernel(const float* __restrict__ W, u16* __restrict__ P0,
                                    u16* __restrict__ P1, u16* __restrict__ P2,
                                    int R, int C) {
  __shared__ float t[32][33];
  const int bz = blockIdx.z;
  const float* Wz = W + (size_t)bz * R * C;
  const size_t oofs = (size_t)bz * R * C;
  const int r0 = blockIdx.x * 32, c0 = blockIdx.y * 32;
  const int tx = threadIdx.x, ty = threadIdx.y;  // (32,8)
#pragma unroll
  for (int i = 0; i < 4; ++i)
    t[ty + i * 8][tx] = Wz[(size_t)(r0 + ty + i * 8) * C + c0 + tx];
  __syncthreads();
#pragma unroll
  for (int i = 0; i < 4; ++i) {
    const int c_raw = c0 + ty + i * 8, r = r0 + tx;
    const int c = PERM ? ((c_raw < FDIM_C) ? (c_raw * 2) : ((c_raw - FDIM_C) * 2 + 1)) : c_raw;
    const float x = t[tx][ty + i * 8];
    const size_t idx = oofs + (size_t)c * R + r;
    const u16 h = f2bf(x);
    P0[idx] = h;
    const float hf = bf2f(h);
    const u16 m = f2bf(x - hf);
    P1[idx] = m;
    if (NP >= 3) {
      const float mf = bf2f(m);
      P2[idx] = f2bf(x - hf - mf);
    }
  }
}

// ---------------------------------------------------------------------------
// 256x256-tile 8-phase split-K' MFMA GEMM.
// Sync rule (m152 lesson): every vmcnt(N) that gates cross-wave LDS visibility
// sits IMMEDIATELY BEFORE an s_barrier, and the dependent ds_reads come after
// that barrier. Steady state: vmcnt(4) at PH1-end (covers cur-tile kh1) and
// PH3-end (covers next-tile kh0); never drains to 0 except the final tile.
// ---------------------------------------------------------------------------
template <int NT, bool RELU, int OSPL, int MIX>
__global__ __launch_bounds__(512, 2) void gemm256(
    const u16* __restrict__ A0, const u16* __restrict__ A1, const u16* __restrict__ A2,
    const u16* __restrict__ B0, const u16* __restrict__ B1, const u16* __restrict__ B2,
    const float* __restrict__ bias, float* __restrict__ outF,
    u16* __restrict__ O0, u16* __restrict__ O1, u16* __restrict__ O2,
    const float* __restrict__ noise_k, const float* __restrict__ wvec,
    float* __restrict__ mixout, int kidx,
    int Kd, int kpsl, int ntiles) {
  __shared__ __align__(16) u16 lds[65536];  // 128 KiB
  const int tid = threadIdx.x;
  const int lane = tid & 63;
  const int wave = tid >> 6;
  const int wm = wave >> 2, wn = wave & 3;
  const int hi2 = tid >> 8, row_s = tid & 255;
  const int kmask = (1 << kpsl) - 1;

  // XCD-bijective swizzle (nwg = 256, gx = 4)
  const int orig = (int)(blockIdx.y * 4 + blockIdx.x);
  const int wg = (orig & 7) * 32 + (orig >> 3);
  const int col0 = (wg & 3) << 8;
  const int row0 = (wg >> 2) << 8;

  auto planes = [&](int kt, const u16*& pa, const u16*& pb, int& ko) {
    const int seg = kt >> kpsl;
    ko = (kt & kmask) << 6;
    if constexpr (NT == 3) {  // TA=[0,0,1] TB=[0,1,0]
      pa = (seg == 2) ? A1 : A0;
      pb = (seg == 1) ? B1 : B0;
    } else {                  // NT==6: TA=[0,0,1,1,0,2] TB=[0,1,0,1,2,0]
      pa = (seg == 2 || seg == 3) ? A1 : ((seg == 5) ? A2 : A0);
      pb = (seg == 1 || seg == 3) ? B1 : ((seg == 4) ? B2 : B0);
    }
  };

  // stage half-tile h of a K-tile: h = {0:A-kh0, 1:B-kh0, 2:A-kh1, 3:B-kh1}
  auto stage = [&](int h, const u16* pa, const u16* pb, int ko, int db) {
    const bool isA = ((h & 1) == 0);
    const int kh = h >> 1;
    const u16* base = isA ? pa : pb;
    const int rb = isA ? row0 : col0;
    const int ldsoff = db * 32768 + (isA ? 0 : 16384);
#pragma unroll
    for (int it = 0; it < 2; ++it) {
      const u16* src = base + (size_t)(rb + row_s) * Kd + ko + (kh * 4 + it * 2 + hi2) * 8;
      gload_lds16(src, &lds[ldsoff + (kh * 1024 + it * 512 + wave * 64) * 8]);
    }
  };

  auto rdA = [&](int fm, int ks, int db) -> bf16x8 {
    const int kb = ks * 4 + (lane >> 4);
    const int r = wm * 128 + fm * 16 + (lane & 15);
    return *(const bf16x8*)&lds[db * 32768 + kb * 2048 + r * 8];
  };
  auto rdB = [&](int fn, int ks, int db) -> bf16x8 {
    const int kb = ks * 4 + (lane >> 4);
    const int r = wn * 64 + fn * 16 + (lane & 15);
    return *(const bf16x8*)&lds[db * 32768 + 16384 + kb * 2048 + r * 8];
  };

  f32x4 acc[8][4] = {};

  {  // prologue: fully stage tile 0; vmcnt(4)+barrier makes kh0 visible to ALL
    const u16 *pa, *pb; int ko;
    planes(0, pa, pb, ko);
    stage(0, pa, pb, ko, 0); stage(1, pa, pb, ko, 0);
    stage(2, pa, pb, ko, 0); stage(3, pa, pb, ko, 0);
    asm volatile("s_waitcnt vmcnt(4)" ::: "memory");
    __builtin_amdgcn_s_barrier();
  }

  for (int kt = 0; kt < ntiles; ++kt) {
    const int cb = kt & 1, nb = cb ^ 1;
    const bool notlast = (kt + 1 < ntiles);
    const u16 *npa = A0, *npb = B0; int nko = 0;
    if (notlast) planes(kt + 1, npa, npb, nko);
    bf16x8 aR[4], bR[4];

    // ---- PH0: ks=0, fm 0-3 (kh0 visible since last barrier) ----
#pragma unroll
    for (int fn = 0; fn < 4; ++fn) bR[fn] = rdB(fn, 0, cb);
#pragma unroll
    for (int fm = 0; fm < 4; ++fm) aR[fm] = rdA(fm, 0, cb);
    if (notlast) stage(0, npa, npb, nko, nb);
    __builtin_amdgcn_s_barrier();
    asm volatile("s_waitcnt lgkmcnt(0)" ::: "memory");
    __builtin_amdgcn_sched_barrier(0);
    __builtin_amdgcn_s_setprio(1);
#pragma unroll
    for (int fm = 0; fm < 4; ++fm)
#pragma unroll
      for (int fn = 0; fn < 4; ++fn)
        acc[fm][fn] = __builtin_amdgcn_mfma_f32_16x16x32_bf16(aR[fm], bR[fn], acc[fm][fn], 0, 0, 0);
    __builtin_amdgcn_s_setprio(0);
    __builtin_amdgcn_s_barrier();

    // ---- PH1: ks=0, fm 4-7 ----
#pragma unroll
    for (int fm = 0; fm < 4; ++fm) aR[fm] = rdA(4 + fm, 0, cb);
    if (notlast) stage(1, npa, npb, nko, nb);
    __builtin_amdgcn_s_barrier();
    asm volatile("s_waitcnt lgkmcnt(0)" ::: "memory");
    __builtin_amdgcn_sched_barrier(0);
    __builtin_amdgcn_s_setprio(1);
#pragma unroll
    for (int fm = 0; fm < 4; ++fm)
#pragma unroll
      for (int fn = 0; fn < 4; ++fn)
        acc[4 + fm][fn] = __builtin_amdgcn_mfma_f32_16x16x32_bf16(aR[fm], bR[fn], acc[4 + fm][fn], 0, 0, 0);
    __builtin_amdgcn_s_setprio(0);
    // cur-tile kh1 (oldest 4 loads) must land before PH2's reads, in ALL waves
    if (notlast) { asm volatile("s_waitcnt vmcnt(4)" ::: "memory"); }
    else         { asm volatile("s_waitcnt vmcnt(0)" ::: "memory"); }
    __builtin_amdgcn_s_barrier();

    // ---- PH2: ks=1, fm 0-3 ----
#pragma unroll
    for (int fn = 0; fn < 4; ++fn) bR[fn] = rdB(fn, 1, cb);
#pragma unroll
    for (int fm = 0; fm < 4; ++fm) aR[fm] = rdA(fm, 1, cb);
    if (notlast) stage(2, npa, npb, nko, nb);
    __builtin_amdgcn_s_barrier();
    asm volatile("s_waitcnt lgkmcnt(0)" ::: "memory");
    __builtin_amdgcn_sched_barrier(0);
    __builtin_amdgcn_s_setprio(1);
#pragma unroll
    for (int fm = 0; fm < 4; ++fm)
#pragma unroll
      for (int fn = 0; fn < 4; ++fn)
        acc[fm][fn] = __builtin_amdgcn_mfma_f32_16x16x32_bf16(aR[fm], bR[fn], acc[fm][fn], 0, 0, 0);
    __builtin_amdgcn_s_setprio(0);
    __builtin_amdgcn_s_barrier();

    // ---- PH3: ks=1, fm 4-7 ----
#pragma unroll
    for (int fm = 0; fm < 4; ++fm) aR[fm] = rdA(4 + fm, 1, cb);
    if (notlast) stage(3, npa, npb, nko, nb);
    __builtin_amdgcn_s_barrier();
    asm volatile("s_waitcnt lgkmcnt(0)" ::: "memory");
    __builtin_amdgcn_sched_barrier(0);
    __builtin_amdgcn_s_setprio(1);
#pragma unroll
    for (int fm = 0; fm < 4; ++fm)
#pragma unroll
      for (int fn = 0; fn < 4; ++fn)
        acc[4 + fm][fn] = __builtin_amdgcn_mfma_f32_16x16x32_bf16(aR[fm], bR[fn], acc[4 + fm][fn], 0, 0, 0);
    __builtin_amdgcn_s_setprio(0);
    // next-tile kh0 (oldest 4 of the 8 in flight) must land before next PH0
    if (notlast) { asm volatile("s_waitcnt vmcnt(4)" ::: "memory"); }
    __builtin_amdgcn_s_barrier();
  }

  // epilogue: D layout col = lane&15, row = (lane>>4)*4 + r  [m89/m91 verified]
  const int hi4 = lane >> 4, rl = lane & 15;
#pragma unroll
  for (int fm = 0; fm < 8; ++fm)
#pragma unroll
    for (int fn = 0; fn < 4; ++fn)
#pragma unroll
      for (int r = 0; r < 4; ++r) {
        const int row = row0 + wm * 128 + fm * 16 + hi4 * 4 + r;
        const int col = col0 + wn * 64 + fn * 16 + rl;
        if constexpr (MIX > 0) {
          // permuted cols: even = mean_f, odd = logvar_f, f = col>>1
          const int f = col >> 1;
          const int ocol = (col & 1) ? (f + FDIM_C) : f;
          const float y = acc[fm][fn][r] + bias[ocol];
          const float other = __shfl_xor(y, 1);
          if (!(lane & 1)) {
            const float sample = y + noise_k[(size_t)row * FDIM_C + f] * expf(0.5f * other);
            const float v = wvec[row * KMIX + kidx] * sample;
            float* op = &mixout[(size_t)row * FDIM_C + f];
            if constexpr (MIX == 1) *op = v; else *op += v;
          }
        } else {
          float y = acc[fm][fn][r] + bias[col];
          if (RELU) y = fmaxf(y, 0.0f);
          const size_t idx = (size_t)row * HDIM_C + col;
          if constexpr (OSPL == 0) {
            outF[idx] = y;
          } else {
            const u16 h = f2bf(y);
            const float hf = bf2f(h);
            const u16 m = f2bf(y - hf);
            O0[idx] = h;
            O1[idx] = m;
            if constexpr (OSPL == 3) {
              const float mf = bf2f(m);
              O2[idx] = f2bf(y - hf - mf);
            }
          }
        }
      }
}

// ---------------------------------------------------------------------------
// logits = h2 @ pw2 + pb2 ; softmax ; gumbel ; argmax ; mixture weights
// ---------------------------------------------------------------------------
__global__ void p2_weights_kernel(const float* __restrict__ h2, const float* __restrict__ pw2,
                                  const float* __restrict__ pb2, const float* __restrict__ gu,
                                  float* __restrict__ w) {
  const int n = blockIdx.x * 4 + (threadIdx.x >> 6);
  const int lane = threadIdx.x & 63;
  const float* hrow = h2 + (size_t)n * HDIM_C;
  double acc[KMIX] = {0, 0, 0, 0, 0};
  const int c0 = lane * 16;
#pragma unroll
  for (int jj = 0; jj < 16; ++jj) {
    const int cc = c0 + jj;
    const double hv = (double)hrow[cc];
#pragma unroll
    for (int kk = 0; kk < KMIX; ++kk)
      acc[kk] += hv * (double)pw2[cc * KMIX + kk];
  }
#pragma unroll
  for (int offs = 32; offs >= 1; offs >>= 1)
#pragma unroll
    for (int kk = 0; kk < KMIX; ++kk)
      acc[kk] += __shfl_down(acc[kk], offs);
  if (lane == 0) {
    double lg[KMIX], mx = -1e300;
#pragma unroll
    for (int kk = 0; kk < KMIX; ++kk) {
      lg[kk] = acc[kk] + (double)pb2[kk];
      if (lg[kk] > mx) mx = lg[kk];
    }
    double e[KMIX], s = 0.0;
#pragma unroll
    for (int kk = 0; kk < KMIX; ++kk) { e[kk] = exp(lg[kk] - mx); s += e[kk]; }
    int idx = 0; double zb = -1e300;
#pragma unroll
    for (int kk = 0; kk < KMIX; ++kk) {
      const double ps = e[kk] / s;
      const double u = (double)gu[n * KMIX + kk];
      const double g = -log(-log(u + 1e-20) + 1e-20);
      const double zz = log(ps + 1e-20) + g;
      if (zz > zb) { zb = zz; idx = kk; }
    }
#pragma unroll
    for (int kk = 0; kk < KMIX; ++kk)
      w[n * KMIX + kk] = (float)((e[kk] / s + (kk == idx ? 5.0 : 0.0)) / 6.0);
  }
}

// ---------------------------------------------------------------------------
extern "C" void kernel_launch(void* const* d_in, const int* in_sizes, int n_in,
                              void* d_out, int out_size, void* d_ws, size_t ws_size,
                              hipStream_t stream) {
  const float* c   = (const float*)d_in[0];
  const float* noise = (const float*)d_in[2];
  const float* gu  = (const float*)d_in[3];
  const float* pw0 = (const float*)d_in[4];
  const float* pb0 = (const float*)d_in[5];
  const float* pw1 = (const float*)d_in[6];
  const float* pb1 = (const float*)d_in[7];
  const float* pw2 = (const float*)d_in[8];
  const float* pb2 = (const float*)d_in[9];
  const float* gw0 = (const float*)d_in[10];
  const float* gb0 = (const float*)d_in[11];
  const float* gw1 = (const float*)d_in[12];
  const float* gb1 = (const float*)d_in[13];
  const float* gw2 = (const float*)d_in[14];
  const float* gb2 = (const float*)d_in[15];
  float* out = (float*)d_out;

  char* ws = (char*)d_ws;
  size_t off = 0;
  auto alloc = [&](size_t bytes) -> char* {
    off = (off + 255) & ~(size_t)255;
    char* p = ws + off;
    off += bytes;
    return p;
  };

  const size_t NCp = (size_t)N_ROWS * CDIM_C * 2;
  const size_t NHp = (size_t)N_ROWS * HDIM_C * 2;
  u16* cH = (u16*)alloc(NCp);
  u16* cM = (u16*)alloc(NCp);
  u16* cL = (u16*)alloc(NCp);
  u16* pw0T0 = (u16*)alloc((size_t)CDIM_C * HDIM_C * 2);
  u16* pw0T1 = (u16*)alloc((size_t)CDIM_C * HDIM_C * 2);
  u16* pw0T2 = (u16*)alloc((size_t)CDIM_C * HDIM_C * 2);
  u16* pw1T0 = (u16*)alloc((size_t)HDIM_C * HDIM_C * 2);
  u16* pw1T1 = (u16*)alloc((size_t)HDIM_C * HDIM_C * 2);
  u16* pw1T2 = (u16*)alloc((size_t)HDIM_C * HDIM_C * 2);
  u16* hH = (u16*)alloc(NHp);
  u16* hM = (u16*)alloc(NHp);
  u16* hL = (u16*)alloc(NHp);
  float* h2 = (float*)alloc((size_t)N_ROWS * HDIM_C * 4);
  float* wbuf = (float*)alloc((size_t)N_ROWS * KMIX * 4);
  u16* gw0T0 = (u16*)alloc((size_t)KMIX * CDIM_C * HDIM_C * 2);
  u16* gw0T1 = (u16*)alloc((size_t)KMIX * CDIM_C * HDIM_C * 2);
  u16* gw1T0 = (u16*)alloc((size_t)KMIX * HDIM_C * HDIM_C * 2);
  u16* gw1T1 = (u16*)alloc((size_t)KMIX * HDIM_C * HDIM_C * 2);
  u16* gw2T0 = (u16*)alloc((size_t)KMIX * HDIM_C * HDIM_C * 2);
  u16* gw2T1 = (u16*)alloc((size_t)KMIX * HDIM_C * HDIM_C * 2);
  u16* g2b = (u16*)alloc(NHp);
  u16* g1a = hH;   // h planes dead after P1
  u16* g1b = hM;
  u16* g2a = hL;
  (void)ws_size; (void)in_sizes; (void)n_in; (void)out_size;

  // ---- prep ----
  split3_kernel<<<2048, 256, 0, stream>>>(c, cH, cM, cL, (size_t)N_ROWS * CDIM_C);
  transp_split_kernel<3, false><<<dim3(CDIM_C / 32, HDIM_C / 32, 1), dim3(32, 8), 0, stream>>>(
      pw0, pw0T0, pw0T1, pw0T2, CDIM_C, HDIM_C);
  transp_split_kernel<3, false><<<dim3(HDIM_C / 32, HDIM_C / 32, 1), dim3(32, 8), 0, stream>>>(
      pw1, pw1T0, pw1T1, pw1T2, HDIM_C, HDIM_C);
  transp_split_kernel<2, false><<<dim3(CDIM_C / 32, HDIM_C / 32, KMIX), dim3(32, 8), 0, stream>>>(
      gw0, gw0T0, gw0T1, nullptr, CDIM_C, HDIM_C);
  transp_split_kernel<2, false><<<dim3(HDIM_C / 32, HDIM_C / 32, KMIX), dim3(32, 8), 0, stream>>>(
      gw1, gw1T0, gw1T1, nullptr, HDIM_C, HDIM_C);
  transp_split_kernel<2, true><<<dim3(HDIM_C / 32, HDIM_C / 32, KMIX), dim3(32, 8), 0, stream>>>(
      gw2, gw2T0, gw2T1, nullptr, HDIM_C, HDIM_C);

  const dim3 gg(HDIM_C / 256, N_ROWS / 256);  // (4, 64) = 256 wgs

  // ---- P network (6-term stacked K', ~fp32-exact for argmax safety) ----
  gemm256<6, true, 3, 0><<<gg, 512, 0, stream>>>(
      cH, cM, cL, pw0T0, pw0T1, pw0T2, pb0, nullptr, hH, hM, hL,
      nullptr, nullptr, nullptr, 0, CDIM_C, 3, 48);
  gemm256<6, true, 0, 0><<<gg, 512, 0, stream>>>(
      hH, hM, hL, pw1T0, pw1T1, pw1T2, pb1, h2, nullptr, nullptr, nullptr,
      nullptr, nullptr, nullptr, 0, HDIM_C, 4, 96);
  p2_weights_kernel<<<N_ROWS / 4, 256, 0, stream>>>(h2, pw2, pb2, gu, wbuf);

  // ---- G network (3-term stacked K') + fused mix epilogue ----
  for (int k = 0; k < KMIX; ++k) {
    gemm256<3, true, 2, 0><<<gg, 512, 0, stream>>>(
        cH, cM, nullptr,
        gw0T0 + (size_t)k * CDIM_C * HDIM_C, gw0T1 + (size_t)k * CDIM_C * HDIM_C, nullptr,
        gb0 + k * HDIM_C, nullptr, g1a, g1b, nullptr,
        nullptr, nullptr, nullptr, 0, CDIM_C, 3, 24);
    gemm256<3, true, 2, 0><<<gg, 512, 0, stream>>>(
        g1a, g1b, nullptr,
        gw1T0 + (size_t)k * HDIM_C * HDIM_C, gw1T1 + (size_t)k * HDIM_C * HDIM_C, nullptr,
        gb1 + k * HDIM_C, nullptr, g2a, g2b, nullptr,
        nullptr, nullptr, nullptr, 0, HDIM_C, 4, 48);
    if (k == 0)
      gemm256<3, false, 0, 1><<<gg, 512, 0, stream>>>(
          g2a, g2b, nullptr,
          gw2T0 + (size_t)k * HDIM_C * HDIM_C, gw2T1 + (size_t)k * HDIM_C * HDIM_C, nullptr,
          gb2 + k * HDIM_C, nullptr, nullptr, nullptr, nullptr,
          noise + (size_t)k * N_ROWS * FDIM_C, wbuf, out, k, HDIM_C, 4, 48);
    else
      gemm256<3, false, 0, 2><<<gg, 512, 0, stream>>>(
          g2a, g2b, nullptr,
          gw2T0 + (size_t)k * HDIM_C * HDIM_C, gw2T1 + (size_t)k * HDIM_C * HDIM_C, nullptr,
          gb2 + k * HDIM_C, nullptr, nullptr, nullptr, nullptr,
          noise + (size_t)k * N_ROWS * FDIM_C, wbuf, out, k, HDIM_C, 4, 48);
  }
}